// Round 5
// baseline (402.713 us; speedup 1.0000x reference)
//
#include <hip/hip_runtime.h>
#include <stdint.h>

#define MDIM 2048
#define KDIM 4096
#define NDIM 8192
#define NG   32            // K / GROUP_SIZE
#define QROW 2048          // int32 per qweight row (each int32 holds one byte = 2 nibbles)
#define LSTR 36            // padded LDS row stride (f16 units): 32 data + 4 pad

typedef __attribute__((ext_vector_type(4))) float    f32x4;
typedef __attribute__((ext_vector_type(2))) _Float16 f16x2;
typedef __attribute__((ext_vector_type(8))) _Float16 f16x8;
typedef __attribute__((ext_vector_type(4))) int      i32x4;

#define CVT2(a,b) __builtin_bit_cast(f16x2, __builtin_amdgcn_cvt_pkrtz((a),(b)))
#define BCU(x)    __builtin_bit_cast(unsigned, (x))
#define BCH2(x)   __builtin_bit_cast(f16x2, (x))

// 128x128 tile, BK=32, 4 waves (2x2), dbuf LDS + reg-prefetch pipeline.
// LDS rows padded to 36 f16 (72 B): frag-read bank starts 18*r mod 32 -> 2-way (free).
// k-order is IDENTITY on both A and B (round-3 verbatim arithmetic).
__global__ __launch_bounds__(256, 4) void qlin_kernel(
    const float* __restrict__ A,       // [M,K] f32 (fp16-valued)
    const int*   __restrict__ qw,      // [N, K/2] int32, one byte each; lo nibble = even k
    const float* __restrict__ scales,  // [N, 32] f32
    const float* __restrict__ zeros,   // [N, 32] f32
    const float* __restrict__ bias,    // [N] f32
    float* __restrict__ out)           // [M,N] f32
{
  __shared__ _Float16 As[2][128 * LSTR];
  __shared__ _Float16 Bs[2][128 * LSTR];

  const int tid  = threadIdx.x;
  const int wave = tid >> 6;
  const int lane = tid & 63;

  // bijective XCD swizzle: 1024 blocks, 8 XCDs -> 128 contiguous per XCD
  const int lid = blockIdx.y * gridDim.x + blockIdx.x;
  const int swz = (lid & 7) * 128 + (lid >> 3);
  const int n0 = (swz & 63) << 7;
  const int m0 = (swz >> 6) << 7;

  const int wm = (wave >> 1) << 6;
  const int wn = (wave & 1) << 6;

  f32x4 acc[4][4] = {};

  // staging: row r4 (and r4+64), 8-element k-chunk c4
  const int r4 = tid >> 2;      // 0..63
  const int c4 = tid & 3;       // 0..3

  const float* aP0 = A + (size_t)(m0 + r4) * KDIM + c4 * 8;
  const float* aP1 = aP0 + (size_t)64 * KDIM;
  const int*   qP0 = qw + (size_t)(n0 + r4) * QROW + c4 * 4;
  const int*   qP1 = qP0 + (size_t)64 * QROW;
  const float* sP0 = scales + (size_t)(n0 + r4) * NG;
  const float* zP0 = zeros  + (size_t)(n0 + r4) * NG;
  const float* sP1 = sP0 + (size_t)64 * NG;
  const float* zP1 = zP0 + (size_t)64 * NG;

  const int aD0 = r4 * LSTR + c4 * 8;
  const int aD1 = (r4 + 64) * LSTR + c4 * 8;

  // fragment addressing: row = base + (lane&15), k-chunk = lane>>4
  const int fr = lane & 15;
  const int k0 = (lane >> 4) * 8;
  const int ra0 = (wm +  0 + fr) * LSTR + k0;
  const int ra1 = (wm + 16 + fr) * LSTR + k0;
  const int ra2 = (wm + 32 + fr) * LSTR + k0;
  const int ra3 = (wm + 48 + fr) * LSTR + k0;
  const int rb0 = (wn +  0 + fr) * LSTR + k0;
  const int rb1 = (wn + 16 + fr) * LSTR + k0;
  const int rb2 = (wn + 32 + fr) * LSTR + k0;
  const int rb3 = (wn + 48 + fr) * LSTR + k0;

  // prefetch registers (live across one iteration)
  f32x4 pa0, pa1, pa2, pa3;
  i32x4 pq0, pq1;
  float psf0, pzf0, psf1, pzf1;

#define ISSUE(KT) do {                                                        \
    __builtin_memcpy(&pa0, aP0 + (size_t)(KT) * 32,     16);                  \
    __builtin_memcpy(&pa1, aP0 + (size_t)(KT) * 32 + 4, 16);                  \
    __builtin_memcpy(&pa2, aP1 + (size_t)(KT) * 32,     16);                  \
    __builtin_memcpy(&pa3, aP1 + (size_t)(KT) * 32 + 4, 16);                  \
    __builtin_memcpy(&pq0, qP0 + (size_t)(KT) * 16, 16);                      \
    __builtin_memcpy(&pq1, qP1 + (size_t)(KT) * 16, 16);                      \
    const int g_ = (KT) >> 2;                                                 \
    psf0 = sP0[g_]; pzf0 = zP0[g_];                                           \
    psf1 = sP1[g_]; pzf1 = zP1[g_];                                           \
  } while (0)

  // dequant one i32x4 (8 weights, identity k-order) into 16B at DST
#define DEQ4(PQ, SF, ZF, DST) do {                                            \
    const _Float16 sh_ = (_Float16)(SF);                                      \
    const _Float16 bh_ = (_Float16)(-(ZF) * (SF));                            \
    const f16x2 s2_ = {sh_, sh_}, b2_ = {bh_, bh_};                           \
    const f16x2 k2_ = {(_Float16)1024.0f, (_Float16)1024.0f};                 \
    uint4 bw_;                                                                \
    {                                                                         \
      unsigned Bb_ = (unsigned)(PQ).x & 0xFFu;                                \
      unsigned bits_ = ((Bb_ | (Bb_ << 12)) & 0x000F000Fu) | 0x64006400u;     \
      bw_.x = BCU((f16x2)((BCH2(bits_) - k2_) * s2_ + b2_));                  \
    }                                                                         \
    {                                                                         \
      unsigned Bb_ = (unsigned)(PQ).y & 0xFFu;                                \
      unsigned bits_ = ((Bb_ | (Bb_ << 12)) & 0x000F000Fu) | 0x64006400u;     \
      bw_.y = BCU((f16x2)((BCH2(bits_) - k2_) * s2_ + b2_));                  \
    }                                                                         \
    {                                                                         \
      unsigned Bb_ = (unsigned)(PQ).z & 0xFFu;                                \
      unsigned bits_ = ((Bb_ | (Bb_ << 12)) & 0x000F000Fu) | 0x64006400u;     \
      bw_.z = BCU((f16x2)((BCH2(bits_) - k2_) * s2_ + b2_));                  \
    }                                                                         \
    {                                                                         \
      unsigned Bb_ = (unsigned)(PQ).w & 0xFFu;                                \
      unsigned bits_ = ((Bb_ | (Bb_ << 12)) & 0x000F000Fu) | 0x64006400u;     \
      bw_.w = BCU((f16x2)((BCH2(bits_) - k2_) * s2_ + b2_));                  \
    }                                                                         \
    __builtin_memcpy((DST), &bw_, 16);                                        \
  } while (0)

#define STAGE(P) do {                                                         \
    uint4 aw0_;                                                               \
    aw0_.x = BCU(CVT2(pa0.x, pa0.y));                                         \
    aw0_.y = BCU(CVT2(pa0.z, pa0.w));                                         \
    aw0_.z = BCU(CVT2(pa1.x, pa1.y));                                         \
    aw0_.w = BCU(CVT2(pa1.z, pa1.w));                                         \
    __builtin_memcpy(&As[P][aD0], &aw0_, 16);                                 \
    uint4 aw1_;                                                               \
    aw1_.x = BCU(CVT2(pa2.x, pa2.y));                                         \
    aw1_.y = BCU(CVT2(pa2.z, pa2.w));                                         \
    aw1_.z = BCU(CVT2(pa3.x, pa3.y));                                         \
    aw1_.w = BCU(CVT2(pa3.z, pa3.w));                                         \
    __builtin_memcpy(&As[P][aD1], &aw1_, 16);                                 \
    DEQ4(pq0, psf0, pzf0, &Bs[P][aD0]);                                       \
    DEQ4(pq1, psf1, pzf1, &Bs[P][aD1]);                                       \
  } while (0)

#define COMPUTE(P) do {                                                       \
    f16x8 af[4], bfr[4];                                                      \
    __builtin_memcpy(&af[0], &As[P][ra0], 16);                                \
    __builtin_memcpy(&af[1], &As[P][ra1], 16);                                \
    __builtin_memcpy(&af[2], &As[P][ra2], 16);                                \
    __builtin_memcpy(&af[3], &As[P][ra3], 16);                                \
    __builtin_memcpy(&bfr[0], &Bs[P][rb0], 16);                               \
    __builtin_memcpy(&bfr[1], &Bs[P][rb1], 16);                               \
    __builtin_memcpy(&bfr[2], &Bs[P][rb2], 16);                               \
    __builtin_memcpy(&bfr[3], &Bs[P][rb3], 16);                               \
    _Pragma("unroll")                                                         \
    for (int i = 0; i < 4; ++i)                                               \
      _Pragma("unroll")                                                       \
      for (int j = 0; j < 4; ++j)                                             \
        acc[i][j] = __builtin_amdgcn_mfma_f32_16x16x32_f16(af[i], bfr[j],     \
                                                           acc[i][j], 0, 0, 0); \
  } while (0)

  // prologue: tile 0
  ISSUE(0);
  STAGE(0);
  __syncthreads();

#pragma clang loop unroll(disable)
  for (int kt = 0; kt < 127; ++kt) {
    const int p = kt & 1;
    ISSUE(kt + 1);      // global loads in flight across COMPUTE
    COMPUTE(p);
    STAGE(p ^ 1);       // vmcnt wait lands here, after MFMA
    __syncthreads();
  }
  COMPUTE(1);           // tile 127

#undef ISSUE
#undef DEQ4
#undef STAGE
#undef COMPUTE

  // epilogue: C/D layout col = lane&15, row = (lane>>4)*4 + reg
  const int cr = (lane >> 4) << 2;
  const int cc = lane & 15;
#pragma unroll
  for (int j = 0; j < 4; ++j) {
    const int n = n0 + wn + j * 16 + cc;
    const float bv = bias[n];
#pragma unroll
    for (int i = 0; i < 4; ++i) {
      const int mrow = m0 + wm + i * 16 + cr;
#pragma unroll
      for (int r = 0; r < 4; ++r)
        out[(size_t)(mrow + r) * NDIM + n] = acc[i][j][r] + bv;
    }
  }
}

extern "C" void kernel_launch(void* const* d_in, const int* in_sizes, int n_in,
                              void* d_out, int out_size, void* d_ws, size_t ws_size,
                              hipStream_t stream) {
  const float* A      = (const float*)d_in[0];
  const int*   qwp    = (const int*)d_in[1];
  const float* scales = (const float*)d_in[2];
  const float* zerosp = (const float*)d_in[3];
  const float* biasp  = (const float*)d_in[4];
  float*       outp   = (float*)d_out;

  dim3 grid(NDIM / 128, MDIM / 128);  // 64 x 16 = 1024 blocks
  qlin_kernel<<<grid, 256, 0, stream>>>(A, qwp, scales, zerosp, biasp, outp);
}

// Round 6
// 303.428 us; speedup vs baseline: 1.3272x; 1.3272x over previous
//
#include <hip/hip_runtime.h>
#include <stdint.h>

#define MDIM 2048
#define KDIM 4096
#define NDIM 8192
#define NG   32            // K / GROUP_SIZE
#define QROW 2048          // int32 per qweight row (each int32 holds one byte = 2 nibbles)
#define LSTR 36            // padded LDS row stride (f16 units): 32 data + 4 pad

typedef __attribute__((ext_vector_type(4))) float    f32x4;
typedef __attribute__((ext_vector_type(2))) _Float16 f16x2;
typedef __attribute__((ext_vector_type(8))) _Float16 f16x8;
typedef __attribute__((ext_vector_type(4))) int      i32x4;

#define CVT2(a,b) __builtin_bit_cast(f16x2, __builtin_amdgcn_cvt_pkrtz((a),(b)))
#define BCU(x)    __builtin_bit_cast(unsigned, (x))
#define BCH2(x)   __builtin_bit_cast(f16x2, (x))

// 128x128 tile, BK=32, 4 waves (2x2), dbuf LDS + reg-prefetch pipeline.
// Natural block order (n fast-varying): B panels L2-local per XCD, A read ~once/XCD.
// LDS rows padded to 36 f16: frag-read bank starts 18*r mod 32 -> 2-way (free).
__global__ __launch_bounds__(256, 4) void qlin_kernel(
    const float* __restrict__ A,       // [M,K] f32 (fp16-valued)
    const int*   __restrict__ qw,      // [N, K/2] int32, one byte each; lo nibble = even k
    const float* __restrict__ scales,  // [N, 32] f32
    const float* __restrict__ zeros,   // [N, 32] f32
    const float* __restrict__ bias,    // [N] f32
    float* __restrict__ out)           // [M,N] f32
{
  __shared__ _Float16 As[2][128 * LSTR];
  __shared__ _Float16 Bs[2][128 * LSTR];

  const int tid  = threadIdx.x;
  const int wave = tid >> 6;
  const int lane = tid & 63;

  const int n0 = blockIdx.x << 7;
  const int m0 = blockIdx.y << 7;

  const int wm = (wave >> 1) << 6;
  const int wn = (wave & 1) << 6;

  f32x4 acc[4][4] = {};

  // staging: row r4 (and r4+64), 8-element k-chunk c4
  const int r4 = tid >> 2;      // 0..63
  const int c4 = tid & 3;       // 0..3

  const float* aP0 = A + (size_t)(m0 + r4) * KDIM + c4 * 8;
  const float* aP1 = aP0 + (size_t)64 * KDIM;
  const int*   qP0 = qw + (size_t)(n0 + r4) * QROW + c4 * 4;
  const int*   qP1 = qP0 + (size_t)64 * QROW;
  const float* sP0 = scales + (size_t)(n0 + r4) * NG;
  const float* zP0 = zeros  + (size_t)(n0 + r4) * NG;
  const float* sP1 = sP0 + (size_t)64 * NG;
  const float* zP1 = zP0 + (size_t)64 * NG;

  const int aD0 = r4 * LSTR + c4 * 8;
  const int aD1 = (r4 + 64) * LSTR + c4 * 8;

  // fragment addressing: row = base + (lane&15), k-chunk = lane>>4
  const int fr = lane & 15;
  const int k0 = (lane >> 4) * 8;
  const int ra0 = (wm +  0 + fr) * LSTR + k0;
  const int ra1 = (wm + 16 + fr) * LSTR + k0;
  const int ra2 = (wm + 32 + fr) * LSTR + k0;
  const int ra3 = (wm + 48 + fr) * LSTR + k0;
  const int rb0 = (wn +  0 + fr) * LSTR + k0;
  const int rb1 = (wn + 16 + fr) * LSTR + k0;
  const int rb2 = (wn + 32 + fr) * LSTR + k0;
  const int rb3 = (wn + 48 + fr) * LSTR + k0;

  // prefetch registers (live across one iteration)
  f32x4 pa0, pa1, pa2, pa3;
  i32x4 pq0, pq1;
  float psf0, pzf0, psf1, pzf1;

#define ISSUE(KT) do {                                                        \
    __builtin_memcpy(&pa0, aP0 + (size_t)(KT) * 32,     16);                  \
    __builtin_memcpy(&pa1, aP0 + (size_t)(KT) * 32 + 4, 16);                  \
    __builtin_memcpy(&pa2, aP1 + (size_t)(KT) * 32,     16);                  \
    __builtin_memcpy(&pa3, aP1 + (size_t)(KT) * 32 + 4, 16);                  \
    __builtin_memcpy(&pq0, qP0 + (size_t)(KT) * 16, 16);                      \
    __builtin_memcpy(&pq1, qP1 + (size_t)(KT) * 16, 16);                      \
    const int g_ = (KT) >> 2;                                                 \
    psf0 = sP0[g_]; pzf0 = zP0[g_];                                           \
    psf1 = sP1[g_]; pzf1 = zP1[g_];                                           \
  } while (0)

  // dequant one i32x4 (8 weights, identity k-order) into 16B at DST
#define DEQ4(PQ, SF, ZF, DST) do {                                            \
    const _Float16 sh_ = (_Float16)(SF);                                      \
    const _Float16 bh_ = (_Float16)(-(ZF) * (SF));                            \
    const f16x2 s2_ = {sh_, sh_}, b2_ = {bh_, bh_};                           \
    const f16x2 k2_ = {(_Float16)1024.0f, (_Float16)1024.0f};                 \
    uint4 bw_;                                                                \
    {                                                                         \
      unsigned Bb_ = (unsigned)(PQ).x & 0xFFu;                                \
      unsigned bits_ = ((Bb_ | (Bb_ << 12)) & 0x000F000Fu) | 0x64006400u;     \
      bw_.x = BCU((f16x2)((BCH2(bits_) - k2_) * s2_ + b2_));                  \
    }                                                                         \
    {                                                                         \
      unsigned Bb_ = (unsigned)(PQ).y & 0xFFu;                                \
      unsigned bits_ = ((Bb_ | (Bb_ << 12)) & 0x000F000Fu) | 0x64006400u;     \
      bw_.y = BCU((f16x2)((BCH2(bits_) - k2_) * s2_ + b2_));                  \
    }                                                                         \
    {                                                                         \
      unsigned Bb_ = (unsigned)(PQ).z & 0xFFu;                                \
      unsigned bits_ = ((Bb_ | (Bb_ << 12)) & 0x000F000Fu) | 0x64006400u;     \
      bw_.z = BCU((f16x2)((BCH2(bits_) - k2_) * s2_ + b2_));                  \
    }                                                                         \
    {                                                                         \
      unsigned Bb_ = (unsigned)(PQ).w & 0xFFu;                                \
      unsigned bits_ = ((Bb_ | (Bb_ << 12)) & 0x000F000Fu) | 0x64006400u;     \
      bw_.w = BCU((f16x2)((BCH2(bits_) - k2_) * s2_ + b2_));                  \
    }                                                                         \
    __builtin_memcpy((DST), &bw_, 16);                                        \
  } while (0)

#define STAGE(P) do {                                                         \
    uint4 aw0_;                                                               \
    aw0_.x = BCU(CVT2(pa0.x, pa0.y));                                         \
    aw0_.y = BCU(CVT2(pa0.z, pa0.w));                                         \
    aw0_.z = BCU(CVT2(pa1.x, pa1.y));                                         \
    aw0_.w = BCU(CVT2(pa1.z, pa1.w));                                         \
    __builtin_memcpy(&As[P][aD0], &aw0_, 16);                                 \
    uint4 aw1_;                                                               \
    aw1_.x = BCU(CVT2(pa2.x, pa2.y));                                         \
    aw1_.y = BCU(CVT2(pa2.z, pa2.w));                                         \
    aw1_.z = BCU(CVT2(pa3.x, pa3.y));                                         \
    aw1_.w = BCU(CVT2(pa3.z, pa3.w));                                         \
    __builtin_memcpy(&As[P][aD1], &aw1_, 16);                                 \
    DEQ4(pq0, psf0, pzf0, &Bs[P][aD0]);                                       \
    DEQ4(pq1, psf1, pzf1, &Bs[P][aD1]);                                       \
  } while (0)

#define COMPUTE(P) do {                                                       \
    f16x8 af[4], bfr[4];                                                      \
    __builtin_memcpy(&af[0], &As[P][ra0], 16);                                \
    __builtin_memcpy(&af[1], &As[P][ra1], 16);                                \
    __builtin_memcpy(&af[2], &As[P][ra2], 16);                                \
    __builtin_memcpy(&af[3], &As[P][ra3], 16);                                \
    __builtin_memcpy(&bfr[0], &Bs[P][rb0], 16);                               \
    __builtin_memcpy(&bfr[1], &Bs[P][rb1], 16);                               \
    __builtin_memcpy(&bfr[2], &Bs[P][rb2], 16);                               \
    __builtin_memcpy(&bfr[3], &Bs[P][rb3], 16);                               \
    _Pragma("unroll")                                                         \
    for (int i = 0; i < 4; ++i)                                               \
      _Pragma("unroll")                                                       \
      for (int j = 0; j < 4; ++j)                                             \
        acc[i][j] = __builtin_amdgcn_mfma_f32_16x16x32_f16(af[i], bfr[j],     \
                                                           acc[i][j], 0, 0, 0); \
  } while (0)

  // prologue: tile 0
  ISSUE(0);
  STAGE(0);
  __syncthreads();

#pragma clang loop unroll(disable)
  for (int kt = 0; kt < 127; ++kt) {
    const int p = kt & 1;
    ISSUE(kt + 1);      // global loads in flight across COMPUTE
    COMPUTE(p);
    STAGE(p ^ 1);       // vmcnt wait lands here, after MFMA
    __syncthreads();
  }
  COMPUTE(1);           // tile 127

#undef ISSUE
#undef DEQ4
#undef STAGE
#undef COMPUTE

  // epilogue: C/D layout col = lane&15, row = (lane>>4)*4 + reg
  const int cr = (lane >> 4) << 2;
  const int cc = lane & 15;
#pragma unroll
  for (int j = 0; j < 4; ++j) {
    const int n = n0 + wn + j * 16 + cc;
    const float bv = bias[n];
#pragma unroll
    for (int i = 0; i < 4; ++i) {
      const int mrow = m0 + wm + i * 16 + cr;
#pragma unroll
      for (int r = 0; r < 4; ++r)
        out[(size_t)(mrow + r) * NDIM + n] = acc[i][j][r] + bv;
    }
  }
}

extern "C" void kernel_launch(void* const* d_in, const int* in_sizes, int n_in,
                              void* d_out, int out_size, void* d_ws, size_t ws_size,
                              hipStream_t stream) {
  const float* A      = (const float*)d_in[0];
  const int*   qwp    = (const int*)d_in[1];
  const float* scales = (const float*)d_in[2];
  const float* zerosp = (const float*)d_in[3];
  const float* biasp  = (const float*)d_in[4];
  float*       outp   = (float*)d_out;

  dim3 grid(NDIM / 128, MDIM / 128);  // 64 x 16 = 1024 blocks
  qlin_kernel<<<grid, 256, 0, stream>>>(A, qwp, scales, zerosp, biasp, outp);
}

// Round 7
// 232.268 us; speedup vs baseline: 1.7338x; 1.3064x over previous
//
#include <hip/hip_runtime.h>
#include <stdint.h>

#define MDIM 2048
#define KDIM 4096
#define NDIM 8192
#define NG   32            // K / GROUP_SIZE
#define QROW 2048          // int32 per qweight row (each int32 holds one byte = 2 nibbles)
#define LSTR 36            // fused-fallback LDS row stride

typedef __attribute__((ext_vector_type(4))) float    f32x4;
typedef __attribute__((ext_vector_type(2))) _Float16 f16x2;
typedef __attribute__((ext_vector_type(8))) _Float16 f16x8;
typedef __attribute__((ext_vector_type(4))) int      i32x4;

#define CVT2(a,b) __builtin_bit_cast(f16x2, __builtin_amdgcn_cvt_pkrtz((a),(b)))
#define BCU(x)    __builtin_bit_cast(unsigned, (x))
#define BCH2(x)   __builtin_bit_cast(f16x2, (x))

__device__ __forceinline__ void gload_lds16(const void* g, void* l) {
  __builtin_amdgcn_global_load_lds(
      (const __attribute__((address_space(1))) void*)g,
      (__attribute__((address_space(3))) void*)l, 16, 0, 0);
}

// dequant 4 int32 (8 weights, identity k-order) -> 8 fp16 (verified rounds 3/6)
__device__ __forceinline__ uint4 dequant8(i32x4 q, float sf, float zf) {
  const _Float16 sh = (_Float16)sf;
  const _Float16 bh = (_Float16)(-zf * sf);
  const f16x2 s2 = {sh, sh}, b2 = {bh, bh};
  const f16x2 k2 = {(_Float16)1024.0f, (_Float16)1024.0f};
  uint4 r;
#define DQE(QV, DST) do {                                                   \
    unsigned Bb_ = (unsigned)(QV) & 0xFFu;                                  \
    unsigned bits_ = ((Bb_ | (Bb_ << 12)) & 0x000F000Fu) | 0x64006400u;     \
    DST = BCU((f16x2)((BCH2(bits_) - k2) * s2 + b2));                       \
  } while (0)
  DQE(q.x, r.x); DQE(q.y, r.y); DQE(q.z, r.z); DQE(q.w, r.w);
#undef DQE
  return r;
}

// ============ pass 1a: W dequant -> f16 [N][K] in ws ============
__global__ __launch_bounds__(256) void dequant_w_kernel(
    const int* __restrict__ qw, const float* __restrict__ scales,
    const float* __restrict__ zeros, _Float16* __restrict__ Wf)
{
  const size_t total = (size_t)NDIM * (KDIM / 8);   // one item = 8 weights
  for (size_t t = (size_t)blockIdx.x * blockDim.x + threadIdx.x; t < total;
       t += (size_t)gridDim.x * blockDim.x) {
    i32x4 q;
    __builtin_memcpy(&q, qw + 4 * t, 16);
    const int n = (int)(t >> 9);            // 512 items per row
    const int k = (int)((t & 511) << 3);
    const int g = k >> 7;
    uint4 w = dequant8(q, scales[n * NG + g], zeros[n * NG + g]);
    __builtin_memcpy(Wf + (size_t)n * KDIM + k, &w, 16);
  }
}

// ============ pass 1b: A f32 -> f16 [M][K] in ws ============
__global__ __launch_bounds__(256) void conv_a_kernel(
    const float* __restrict__ A, _Float16* __restrict__ Af)
{
  const size_t total = (size_t)MDIM * (KDIM / 8);
  for (size_t t = (size_t)blockIdx.x * blockDim.x + threadIdx.x; t < total;
       t += (size_t)gridDim.x * blockDim.x) {
    f32x4 v0, v1;
    __builtin_memcpy(&v0, A + 8 * t,     16);
    __builtin_memcpy(&v1, A + 8 * t + 4, 16);
    uint4 h;
    h.x = BCU(CVT2(v0.x, v0.y));
    h.y = BCU(CVT2(v0.z, v0.w));
    h.z = BCU(CVT2(v1.x, v1.y));
    h.w = BCU(CVT2(v1.z, v1.w));
    __builtin_memcpy(Af + 8 * t, &h, 16);
  }
}

// ============ pass 2: f16 GEMM, m97 structure ============
// 128x128 tile, BK=32, 4 waves (2x2), global_load_lds width-16, linear LDS [128][32].
__global__ __launch_bounds__(256) void gemm_f16_kernel(
    const _Float16* __restrict__ Af,   // [M][K]
    const _Float16* __restrict__ Wf,   // [N][K]
    const float* __restrict__ bias,    // [N]
    float* __restrict__ out)           // [M][N]
{
  __shared__ _Float16 As[128 * 32];
  __shared__ _Float16 Bs[128 * 32];

  const int tid  = threadIdx.x;
  const int wave = tid >> 6;
  const int lane = tid & 63;
  const int n0 = blockIdx.x << 7;
  const int m0 = blockIdx.y << 7;
  const int wm = (wave >> 1) << 6;
  const int wn = (wave & 1) << 6;

  f32x4 acc[4][4] = {};

  // gload_lds: LDS flat f16 idx = 2048*i + 512*wave + 8*lane  (HW adds lane*16B)
  //   -> row = 64*i + 16*wave + (lane>>2), k = 8*(lane&3)
  const int srow = 16 * wave + (lane >> 2);
  const int kofs = 8 * (lane & 3);
  const _Float16* aSrc0 = Af + (size_t)(m0 + srow) * KDIM + kofs;
  const _Float16* aSrc1 = aSrc0 + (size_t)64 * KDIM;
  const _Float16* bSrc0 = Wf + (size_t)(n0 + srow) * KDIM + kofs;
  const _Float16* bSrc1 = bSrc0 + (size_t)64 * KDIM;
  _Float16* aDst0 = &As[wave * 512];
  _Float16* aDst1 = &As[2048 + wave * 512];
  _Float16* bDst0 = &Bs[wave * 512];
  _Float16* bDst1 = &Bs[2048 + wave * 512];

  // fragment addressing: row = base + (lane&15), k-chunk = lane>>4
  const int fr = lane & 15;
  const int k0 = (lane >> 4) * 8;
  const int ra0 = (wm +  0 + fr) * 32 + k0;
  const int ra1 = (wm + 16 + fr) * 32 + k0;
  const int ra2 = (wm + 32 + fr) * 32 + k0;
  const int ra3 = (wm + 48 + fr) * 32 + k0;
  const int rb0 = (wn +  0 + fr) * 32 + k0;
  const int rb1 = (wn + 16 + fr) * 32 + k0;
  const int rb2 = (wn + 32 + fr) * 32 + k0;
  const int rb3 = (wn + 48 + fr) * 32 + k0;

#pragma clang loop unroll(disable)
  for (int kt = 0; kt < KDIM / 32; ++kt) {
    const int ko = kt * 32;
    gload_lds16(aSrc0 + ko, aDst0);
    gload_lds16(aSrc1 + ko, aDst1);
    gload_lds16(bSrc0 + ko, bDst0);
    gload_lds16(bSrc1 + ko, bDst1);
    __syncthreads();   // drains vmcnt: LDS tiles complete

    f16x8 af[4], bfr[4];
    __builtin_memcpy(&af[0], &As[ra0], 16);
    __builtin_memcpy(&af[1], &As[ra1], 16);
    __builtin_memcpy(&af[2], &As[ra2], 16);
    __builtin_memcpy(&af[3], &As[ra3], 16);
    __builtin_memcpy(&bfr[0], &Bs[rb0], 16);
    __builtin_memcpy(&bfr[1], &Bs[rb1], 16);
    __builtin_memcpy(&bfr[2], &Bs[rb2], 16);
    __builtin_memcpy(&bfr[3], &Bs[rb3], 16);
#pragma unroll
    for (int i = 0; i < 4; ++i)
#pragma unroll
      for (int j = 0; j < 4; ++j)
        acc[i][j] = __builtin_amdgcn_mfma_f32_16x16x32_f16(af[i], bfr[j], acc[i][j], 0, 0, 0);

    __syncthreads();
  }

  const int cr = (lane >> 4) << 2;
  const int cc = lane & 15;
#pragma unroll
  for (int j = 0; j < 4; ++j) {
    const int n = n0 + wn + j * 16 + cc;
    const float bv = bias[n];
#pragma unroll
    for (int i = 0; i < 4; ++i) {
      const int mrow = m0 + wm + i * 16 + cr;
#pragma unroll
      for (int r = 0; r < 4; ++r)
        out[(size_t)(mrow + r) * NDIM + n] = acc[i][j][r] + bv;
    }
  }
}

// ============ fused fallback (round-6 kernel, verified PASS) ============
__global__ __launch_bounds__(256, 4) void qlin_fused_kernel(
    const float* __restrict__ A, const int* __restrict__ qw,
    const float* __restrict__ scales, const float* __restrict__ zeros,
    const float* __restrict__ bias, float* __restrict__ out)
{
  __shared__ _Float16 As[2][128 * LSTR];
  __shared__ _Float16 Bs[2][128 * LSTR];

  const int tid  = threadIdx.x;
  const int wave = tid >> 6;
  const int lane = tid & 63;
  const int n0 = blockIdx.x << 7;
  const int m0 = blockIdx.y << 7;
  const int wm = (wave >> 1) << 6;
  const int wn = (wave & 1) << 6;

  f32x4 acc[4][4] = {};

  const int r4 = tid >> 2;
  const int c4 = tid & 3;

  const float* aP0 = A + (size_t)(m0 + r4) * KDIM + c4 * 8;
  const float* aP1 = aP0 + (size_t)64 * KDIM;
  const int*   qP0 = qw + (size_t)(n0 + r4) * QROW + c4 * 4;
  const int*   qP1 = qP0 + (size_t)64 * QROW;
  const float* sP0 = scales + (size_t)(n0 + r4) * NG;
  const float* zP0 = zeros  + (size_t)(n0 + r4) * NG;
  const float* sP1 = sP0 + (size_t)64 * NG;
  const float* zP1 = zP0 + (size_t)64 * NG;

  const int aD0 = r4 * LSTR + c4 * 8;
  const int aD1 = (r4 + 64) * LSTR + c4 * 8;

  const int fr = lane & 15;
  const int k0 = (lane >> 4) * 8;
  const int ra0 = (wm +  0 + fr) * LSTR + k0;
  const int ra1 = (wm + 16 + fr) * LSTR + k0;
  const int ra2 = (wm + 32 + fr) * LSTR + k0;
  const int ra3 = (wm + 48 + fr) * LSTR + k0;
  const int rb0 = (wn +  0 + fr) * LSTR + k0;
  const int rb1 = (wn + 16 + fr) * LSTR + k0;
  const int rb2 = (wn + 32 + fr) * LSTR + k0;
  const int rb3 = (wn + 48 + fr) * LSTR + k0;

  f32x4 pa0, pa1, pa2, pa3;
  i32x4 pq0, pq1;
  float psf0, pzf0, psf1, pzf1;

#define ISSUE(KT) do {                                                        \
    __builtin_memcpy(&pa0, aP0 + (size_t)(KT) * 32,     16);                  \
    __builtin_memcpy(&pa1, aP0 + (size_t)(KT) * 32 + 4, 16);                  \
    __builtin_memcpy(&pa2, aP1 + (size_t)(KT) * 32,     16);                  \
    __builtin_memcpy(&pa3, aP1 + (size_t)(KT) * 32 + 4, 16);                  \
    __builtin_memcpy(&pq0, qP0 + (size_t)(KT) * 16, 16);                      \
    __builtin_memcpy(&pq1, qP1 + (size_t)(KT) * 16, 16);                      \
    const int g_ = (KT) >> 2;                                                 \
    psf0 = sP0[g_]; pzf0 = zP0[g_];                                           \
    psf1 = sP1[g_]; pzf1 = zP1[g_];                                           \
  } while (0)

#define STAGE(P) do {                                                         \
    uint4 aw0_;                                                               \
    aw0_.x = BCU(CVT2(pa0.x, pa0.y));                                         \
    aw0_.y = BCU(CVT2(pa0.z, pa0.w));                                         \
    aw0_.z = BCU(CVT2(pa1.x, pa1.y));                                         \
    aw0_.w = BCU(CVT2(pa1.z, pa1.w));                                         \
    __builtin_memcpy(&As[P][aD0], &aw0_, 16);                                 \
    uint4 aw1_;                                                               \
    aw1_.x = BCU(CVT2(pa2.x, pa2.y));                                         \
    aw1_.y = BCU(CVT2(pa2.z, pa2.w));                                         \
    aw1_.z = BCU(CVT2(pa3.x, pa3.y));                                         \
    aw1_.w = BCU(CVT2(pa3.z, pa3.w));                                         \
    __builtin_memcpy(&As[P][aD1], &aw1_, 16);                                 \
    uint4 bw0_ = dequant8(pq0, psf0, pzf0);                                   \
    __builtin_memcpy(&Bs[P][aD0], &bw0_, 16);                                 \
    uint4 bw1_ = dequant8(pq1, psf1, pzf1);                                   \
    __builtin_memcpy(&Bs[P][aD1], &bw1_, 16);                                 \
  } while (0)

#define COMPUTE(P) do {                                                       \
    f16x8 af[4], bfr[4];                                                      \
    __builtin_memcpy(&af[0], &As[P][ra0], 16);                                \
    __builtin_memcpy(&af[1], &As[P][ra1], 16);                                \
    __builtin_memcpy(&af[2], &As[P][ra2], 16);                                \
    __builtin_memcpy(&af[3], &As[P][ra3], 16);                                \
    __builtin_memcpy(&bfr[0], &Bs[P][rb0], 16);                               \
    __builtin_memcpy(&bfr[1], &Bs[P][rb1], 16);                               \
    __builtin_memcpy(&bfr[2], &Bs[P][rb2], 16);                               \
    __builtin_memcpy(&bfr[3], &Bs[P][rb3], 16);                               \
    _Pragma("unroll")                                                         \
    for (int i = 0; i < 4; ++i)                                               \
      _Pragma("unroll")                                                       \
      for (int j = 0; j < 4; ++j)                                             \
        acc[i][j] = __builtin_amdgcn_mfma_f32_16x16x32_f16(af[i], bfr[j],     \
                                                           acc[i][j], 0, 0, 0); \
  } while (0)

  ISSUE(0);
  STAGE(0);
  __syncthreads();

#pragma clang loop unroll(disable)
  for (int kt = 0; kt < 127; ++kt) {
    const int p = kt & 1;
    ISSUE(kt + 1);
    COMPUTE(p);
    STAGE(p ^ 1);
    __syncthreads();
  }
  COMPUTE(1);

#undef ISSUE
#undef STAGE
#undef COMPUTE

  const int cr = (lane >> 4) << 2;
  const int cc = lane & 15;
#pragma unroll
  for (int j = 0; j < 4; ++j) {
    const int n = n0 + wn + j * 16 + cc;
    const float bv = bias[n];
#pragma unroll
    for (int i = 0; i < 4; ++i) {
      const int mrow = m0 + wm + i * 16 + cr;
#pragma unroll
      for (int r = 0; r < 4; ++r)
        out[(size_t)(mrow + r) * NDIM + n] = acc[i][j][r] + bv;
    }
  }
}

extern "C" void kernel_launch(void* const* d_in, const int* in_sizes, int n_in,
                              void* d_out, int out_size, void* d_ws, size_t ws_size,
                              hipStream_t stream) {
  const float* A      = (const float*)d_in[0];
  const int*   qwp    = (const int*)d_in[1];
  const float* scales = (const float*)d_in[2];
  const float* zerosp = (const float*)d_in[3];
  const float* biasp  = (const float*)d_in[4];
  float*       outp   = (float*)d_out;

  const size_t needW = (size_t)NDIM * KDIM * sizeof(_Float16);   // 64 MB
  const size_t needA = (size_t)MDIM * KDIM * sizeof(_Float16);   // 16 MB

  if (ws_size >= needW + needA) {
    _Float16* Wf = (_Float16*)d_ws;
    _Float16* Af = (_Float16*)((char*)d_ws + needW);
    dequant_w_kernel<<<2048, 256, 0, stream>>>(qwp, scales, zerosp, Wf);
    conv_a_kernel<<<2048, 256, 0, stream>>>(A, Af);
    dim3 grid(NDIM / 128, MDIM / 128);  // 64 x 16
    gemm_f16_kernel<<<grid, 256, 0, stream>>>(Af, Wf, biasp, outp);
  } else {
    dim3 grid(NDIM / 128, MDIM / 128);
    qlin_fused_kernel<<<grid, 256, 0, stream>>>(A, qwp, scales, zerosp, biasp, outp);
  }
}

// Round 8
// 185.876 us; speedup vs baseline: 2.1666x; 1.2496x over previous
//
#include <hip/hip_runtime.h>
#include <stdint.h>

#define MDIM 2048
#define KDIM 4096
#define NDIM 8192
#define NG   32            // K / GROUP_SIZE
#define QROW 2048          // int32 per qweight row
#define NT   128           // K-tiles of BK=32
#define LSTR 36            // fused-fallback LDS row stride

typedef __attribute__((ext_vector_type(4))) float    f32x4;
typedef __attribute__((ext_vector_type(2))) _Float16 f16x2;
typedef __attribute__((ext_vector_type(8))) _Float16 f16x8;
typedef __attribute__((ext_vector_type(4))) int      i32x4;

#define CVT2(a,b) __builtin_bit_cast(f16x2, __builtin_amdgcn_cvt_pkrtz((a),(b)))
#define BCU(x)    __builtin_bit_cast(unsigned, (x))
#define BCH2(x)   __builtin_bit_cast(f16x2, (x))

__device__ __forceinline__ void gload_lds16(const void* g, void* l) {
  __builtin_amdgcn_global_load_lds(
      (const __attribute__((address_space(1))) void*)g,
      (__attribute__((address_space(3))) void*)l, 16, 0, 0);
}

// dequant 4 int32 (8 weights, identity k-order) -> 8 fp16 (verified r3/r6/r7)
__device__ __forceinline__ uint4 dequant8(i32x4 q, float sf, float zf) {
  const _Float16 sh = (_Float16)sf;
  const _Float16 bh = (_Float16)(-zf * sf);
  const f16x2 s2 = {sh, sh}, b2 = {bh, bh};
  const f16x2 k2 = {(_Float16)1024.0f, (_Float16)1024.0f};
  uint4 r;
#define DQE(QV, DST) do {                                                   \
    unsigned Bb_ = (unsigned)(QV) & 0xFFu;                                  \
    unsigned bits_ = ((Bb_ | (Bb_ << 12)) & 0x000F000Fu) | 0x64006400u;     \
    DST = BCU((f16x2)((BCH2(bits_) - k2) * s2 + b2));                       \
  } while (0)
  DQE(q.x, r.x); DQE(q.y, r.y); DQE(q.z, r.z); DQE(q.w, r.w);
#undef DQE
  return r;
}

// ============ pass 1a: W dequant -> f16 [N][K] in ws ============
__global__ __launch_bounds__(256) void dequant_w_kernel(
    const int* __restrict__ qw, const float* __restrict__ scales,
    const float* __restrict__ zeros, _Float16* __restrict__ Wf)
{
  const size_t total = (size_t)NDIM * (KDIM / 8);
  for (size_t t = (size_t)blockIdx.x * blockDim.x + threadIdx.x; t < total;
       t += (size_t)gridDim.x * blockDim.x) {
    i32x4 q;
    __builtin_memcpy(&q, qw + 4 * t, 16);
    const int n = (int)(t >> 9);
    const int k = (int)((t & 511) << 3);
    const int g = k >> 7;
    uint4 w = dequant8(q, scales[n * NG + g], zeros[n * NG + g]);
    __builtin_memcpy(Wf + (size_t)n * KDIM + k, &w, 16);
  }
}

// ============ pass 1b: A f32 -> f16 [M][K] in ws ============
__global__ __launch_bounds__(256) void conv_a_kernel(
    const float* __restrict__ A, _Float16* __restrict__ Af)
{
  const size_t total = (size_t)MDIM * (KDIM / 8);
  for (size_t t = (size_t)blockIdx.x * blockDim.x + threadIdx.x; t < total;
       t += (size_t)gridDim.x * blockDim.x) {
    f32x4 v0, v1;
    __builtin_memcpy(&v0, A + 8 * t,     16);
    __builtin_memcpy(&v1, A + 8 * t + 4, 16);
    uint4 h;
    h.x = BCU(CVT2(v0.x, v0.y));
    h.y = BCU(CVT2(v0.z, v0.w));
    h.z = BCU(CVT2(v1.x, v1.y));
    h.w = BCU(CVT2(v1.z, v1.w));
    __builtin_memcpy(Af + 8 * t, &h, 16);
  }
}

// ============ pass 2: f16 GEMM, 256x256 tile, depth-3 counted-vmcnt pipeline ============
// 8 waves (2M x 4N), BK=32, 4 rotating LDS bufs (32KB each: A[256][32] + B[256][32]).
// Swizzle (involution on within-region byte offset o): o ^= ((o>>7)&3)<<4, i.e.
// 16B-chunk index ^= (row>>1)&3. Applied to pre-swizzled global SOURCE (linear
// gload_lds dest) and to ds_read offsets. 16 frag-read lanes -> 2-way banks (free).
__global__ __launch_bounds__(512) void gemm_f16_kernel(
    const _Float16* __restrict__ Af,   // [M][K]
    const _Float16* __restrict__ Wf,   // [N][K]
    const float* __restrict__ bias,    // [N]
    float* __restrict__ out)           // [M][N] f32
{
  __shared__ __align__(16) _Float16 lds[4 * 16384];   // 128 KB

  const int tid  = threadIdx.x;
  const int wave = tid >> 6;
  const int lane = tid & 63;
  const int n0 = blockIdx.x << 8;    // 32 n-blocks
  const int m0 = blockIdx.y << 8;    // 8 m-blocks
  const int wm = (wave >> 2) << 7;   // 0 or 128
  const int wn = (wave & 3) << 6;    // 0,64,128,192

  f32x4 acc[8][4] = {};

  // ---- staging source (pre-swizzled): linear slot tid*16B holds logical
  // (row = tid>>2, chunk = (tid&3) ^ ((tid>>3)&3)) of the 128-row half-tile.
  const int srow   = tid >> 2;
  const int schunk = (tid & 3) ^ ((tid >> 3) & 3);
  const _Float16* aS0 = Af + (size_t)(m0 + srow) * KDIM + schunk * 8;
  const _Float16* aS1 = Af + (size_t)(m0 + 128 + srow) * KDIM + schunk * 8;
  const _Float16* bS0 = Wf + (size_t)(n0 + srow) * KDIM + schunk * 8;
  const _Float16* bS1 = Wf + (size_t)(n0 + 128 + srow) * KDIM + schunk * 8;

#define ISSUE(T) do {                                                  \
    _Float16* d_ = &lds[(((T) & 3) << 14) + (wave << 9)];              \
    const size_t ko_ = (size_t)(T) << 5;                               \
    gload_lds16(aS0 + ko_, d_);                                        \
    gload_lds16(aS1 + ko_, d_ + 4096);                                 \
    gload_lds16(bS0 + ko_, d_ + 8192);                                 \
    gload_lds16(bS1 + ko_, d_ + 12288);                                \
  } while (0)

  // ---- fragment read offsets (swizzled; (row>>1)&3 == (fr>>1)&3 here) ----
  const int fr = lane & 15;
  const int ck = (((lane >> 4) ^ ((fr >> 1) & 3))) << 3;
  int raOff[8], rbOff[4];
#pragma unroll
  for (int i = 0; i < 8; ++i) raOff[i] = (wm + 16 * i + fr) * 32 + ck;
#pragma unroll
  for (int j = 0; j < 4; ++j) rbOff[j] = 8192 + (wn + 16 * j + fr) * 32 + ck;

  // quadrant-structured compute: B frags once, A frags 2-at-a-time
#define COMPUTE(T) do {                                                \
    const int bb_ = ((T) & 3) << 14;                                   \
    f16x8 bf_[4];                                                      \
    _Pragma("unroll")                                                  \
    for (int j = 0; j < 4; ++j)                                        \
      __builtin_memcpy(&bf_[j], &lds[bb_ + rbOff[j]], 16);             \
    _Pragma("unroll")                                                  \
    for (int q = 0; q < 4; ++q) {                                      \
      f16x8 a0_, a1_;                                                  \
      __builtin_memcpy(&a0_, &lds[bb_ + raOff[2 * q]], 16);            \
      __builtin_memcpy(&a1_, &lds[bb_ + raOff[2 * q + 1]], 16);        \
      __builtin_amdgcn_s_setprio(1);                                   \
      _Pragma("unroll")                                                \
      for (int j = 0; j < 4; ++j) {                                    \
        acc[2 * q][j] = __builtin_amdgcn_mfma_f32_16x16x32_f16(        \
            a0_, bf_[j], acc[2 * q][j], 0, 0, 0);                      \
        acc[2 * q + 1][j] = __builtin_amdgcn_mfma_f32_16x16x32_f16(    \
            a1_, bf_[j], acc[2 * q + 1][j], 0, 0, 0);                  \
      }                                                                \
      __builtin_amdgcn_s_setprio(0);                                   \
    }                                                                  \
  } while (0)

  // prologue: 3 tiles in flight
  ISSUE(0); ISSUE(1); ISSUE(2);

#pragma clang loop unroll(disable)
  for (int t = 0; t < NT - 3; ++t) {
    // wait tile t's 4 loads (t+1, t+2 stay in flight), sync, then extend pipe
    asm volatile("s_waitcnt vmcnt(8)" ::: "memory");
    __builtin_amdgcn_s_barrier();
    ISSUE(t + 3);          // -> buf (t-1)&3, freed by the barrier above
    COMPUTE(t);
  }
  asm volatile("s_waitcnt vmcnt(8)" ::: "memory");
  __builtin_amdgcn_s_barrier();
  COMPUTE(NT - 3);
  asm volatile("s_waitcnt vmcnt(4)" ::: "memory");
  __builtin_amdgcn_s_barrier();
  COMPUTE(NT - 2);
  asm volatile("s_waitcnt vmcnt(0)" ::: "memory");
  __builtin_amdgcn_s_barrier();
  COMPUTE(NT - 1);

#undef ISSUE
#undef COMPUTE

  // epilogue: C/D col = lane&15, row = (lane>>4)*4 + reg
  const int cr = (lane >> 4) << 2;
  const int cc = lane & 15;
#pragma unroll
  for (int j = 0; j < 4; ++j) {
    const int n = n0 + wn + j * 16 + cc;
    const float bv = bias[n];
#pragma unroll
    for (int i = 0; i < 8; ++i) {
      const int mrow = m0 + wm + i * 16 + cr;
#pragma unroll
      for (int r = 0; r < 4; ++r)
        out[(size_t)(mrow + r) * NDIM + n] = acc[i][j][r] + bv;
    }
  }
}

// ============ fused fallback (round-6 kernel, verified PASS) ============
__global__ __launch_bounds__(256, 4) void qlin_fused_kernel(
    const float* __restrict__ A, const int* __restrict__ qw,
    const float* __restrict__ scales, const float* __restrict__ zeros,
    const float* __restrict__ bias, float* __restrict__ out)
{
  __shared__ _Float16 As[2][128 * LSTR];
  __shared__ _Float16 Bs[2][128 * LSTR];

  const int tid  = threadIdx.x;
  const int wave = tid >> 6;
  const int lane = tid & 63;
  const int n0 = blockIdx.x << 7;
  const int m0 = blockIdx.y << 7;
  const int wm = (wave >> 1) << 6;
  const int wn = (wave & 1) << 6;

  f32x4 acc[4][4] = {};

  const int r4 = tid >> 2;
  const int c4 = tid & 3;

  const float* aP0 = A + (size_t)(m0 + r4) * KDIM + c4 * 8;
  const float* aP1 = aP0 + (size_t)64 * KDIM;
  const int*   qP0 = qw + (size_t)(n0 + r4) * QROW + c4 * 4;
  const int*   qP1 = qP0 + (size_t)64 * QROW;
  const float* sP0 = scales + (size_t)(n0 + r4) * NG;
  const float* zP0 = zeros  + (size_t)(n0 + r4) * NG;
  const float* sP1 = sP0 + (size_t)64 * NG;
  const float* zP1 = zP0 + (size_t)64 * NG;

  const int aD0 = r4 * LSTR + c4 * 8;
  const int aD1 = (r4 + 64) * LSTR + c4 * 8;

  const int fr = lane & 15;
  const int k0 = (lane >> 4) * 8;
  const int ra0 = (wm +  0 + fr) * LSTR + k0;
  const int ra1 = (wm + 16 + fr) * LSTR + k0;
  const int ra2 = (wm + 32 + fr) * LSTR + k0;
  const int ra3 = (wm + 48 + fr) * LSTR + k0;
  const int rb0 = (wn +  0 + fr) * LSTR + k0;
  const int rb1 = (wn + 16 + fr) * LSTR + k0;
  const int rb2 = (wn + 32 + fr) * LSTR + k0;
  const int rb3 = (wn + 48 + fr) * LSTR + k0;

  f32x4 pa0, pa1, pa2, pa3;
  i32x4 pq0, pq1;
  float psf0, pzf0, psf1, pzf1;

#define ISSUE(KT) do {                                                        \
    __builtin_memcpy(&pa0, aP0 + (size_t)(KT) * 32,     16);                  \
    __builtin_memcpy(&pa1, aP0 + (size_t)(KT) * 32 + 4, 16);                  \
    __builtin_memcpy(&pa2, aP1 + (size_t)(KT) * 32,     16);                  \
    __builtin_memcpy(&pa3, aP1 + (size_t)(KT) * 32 + 4, 16);                  \
    __builtin_memcpy(&pq0, qP0 + (size_t)(KT) * 16, 16);                      \
    __builtin_memcpy(&pq1, qP1 + (size_t)(KT) * 16, 16);                      \
    const int g_ = (KT) >> 2;                                                 \
    psf0 = sP0[g_]; pzf0 = zP0[g_];                                           \
    psf1 = sP1[g_]; pzf1 = zP1[g_];                                           \
  } while (0)

#define STAGE(P) do {                                                         \
    uint4 aw0_;                                                               \
    aw0_.x = BCU(CVT2(pa0.x, pa0.y));                                         \
    aw0_.y = BCU(CVT2(pa0.z, pa0.w));                                         \
    aw0_.z = BCU(CVT2(pa1.x, pa1.y));                                         \
    aw0_.w = BCU(CVT2(pa1.z, pa1.w));                                         \
    __builtin_memcpy(&As[P][aD0], &aw0_, 16);                                 \
    uint4 aw1_;                                                               \
    aw1_.x = BCU(CVT2(pa2.x, pa2.y));                                         \
    aw1_.y = BCU(CVT2(pa2.z, pa2.w));                                         \
    aw1_.z = BCU(CVT2(pa3.x, pa3.y));                                         \
    aw1_.w = BCU(CVT2(pa3.z, pa3.w));                                         \
    __builtin_memcpy(&As[P][aD1], &aw1_, 16);                                 \
    uint4 bw0_ = dequant8(pq0, psf0, pzf0);                                   \
    __builtin_memcpy(&Bs[P][aD0], &bw0_, 16);                                 \
    uint4 bw1_ = dequant8(pq1, psf1, pzf1);                                   \
    __builtin_memcpy(&Bs[P][aD1], &bw1_, 16);                                 \
  } while (0)

#define COMPUTE(P) do {                                                       \
    f16x8 af[4], bfr[4];                                                      \
    __builtin_memcpy(&af[0], &As[P][ra0], 16);                                \
    __builtin_memcpy(&af[1], &As[P][ra1], 16);                                \
    __builtin_memcpy(&af[2], &As[P][ra2], 16);                                \
    __builtin_memcpy(&af[3], &As[P][ra3], 16);                                \
    __builtin_memcpy(&bfr[0], &Bs[P][rb0], 16);                               \
    __builtin_memcpy(&bfr[1], &Bs[P][rb1], 16);                               \
    __builtin_memcpy(&bfr[2], &Bs[P][rb2], 16);                               \
    __builtin_memcpy(&bfr[3], &Bs[P][rb3], 16);                               \
    _Pragma("unroll")                                                         \
    for (int i = 0; i < 4; ++i)                                               \
      _Pragma("unroll")                                                       \
      for (int j = 0; j < 4; ++j)                                             \
        acc[i][j] = __builtin_amdgcn_mfma_f32_16x16x32_f16(af[i], bfr[j],     \
                                                           acc[i][j], 0, 0, 0); \
  } while (0)

  ISSUE(0);
  STAGE(0);
  __syncthreads();

#pragma clang loop unroll(disable)
  for (int kt = 0; kt < 127; ++kt) {
    const int p = kt & 1;
    ISSUE(kt + 1);
    COMPUTE(p);
    STAGE(p ^ 1);
    __syncthreads();
  }
  COMPUTE(1);

#undef ISSUE
#undef STAGE
#undef COMPUTE

  const int cr = (lane >> 4) << 2;
  const int cc = lane & 15;
#pragma unroll
  for (int j = 0; j < 4; ++j) {
    const int n = n0 + wn + j * 16 + cc;
    const float bv = bias[n];
#pragma unroll
    for (int i = 0; i < 4; ++i) {
      const int mrow = m0 + wm + i * 16 + cr;
#pragma unroll
      for (int r = 0; r < 4; ++r)
        out[(size_t)(mrow + r) * NDIM + n] = acc[i][j][r] + bv;
    }
  }
}

extern "C" void kernel_launch(void* const* d_in, const int* in_sizes, int n_in,
                              void* d_out, int out_size, void* d_ws, size_t ws_size,
                              hipStream_t stream) {
  const float* A      = (const float*)d_in[0];
  const int*   qwp    = (const int*)d_in[1];
  const float* scales = (const float*)d_in[2];
  const float* zerosp = (const float*)d_in[3];
  const float* biasp  = (const float*)d_in[4];
  float*       outp   = (float*)d_out;

  const size_t needW = (size_t)NDIM * KDIM * sizeof(_Float16);   // 64 MB
  const size_t needA = (size_t)MDIM * KDIM * sizeof(_Float16);   // 16 MB

  if (ws_size >= needW + needA) {
    _Float16* Wf = (_Float16*)d_ws;
    _Float16* Af = (_Float16*)((char*)d_ws + needW);
    dequant_w_kernel<<<2048, 256, 0, stream>>>(qwp, scales, zerosp, Wf);
    conv_a_kernel<<<2048, 256, 0, stream>>>(A, Af);
    dim3 grid(NDIM / 256, MDIM / 256);  // 32 x 8 = 256 blocks (1/CU)
    gemm_f16_kernel<<<grid, 512, 0, stream>>>(Af, Wf, biasp, outp);
  } else {
    dim3 grid(NDIM / 128, MDIM / 128);
    qlin_fused_kernel<<<grid, 256, 0, stream>>>(A, qwp, scales, zerosp, biasp, outp);
  }
}

// Round 9
// 172.853 us; speedup vs baseline: 2.3298x; 1.0753x over previous
//
#include <hip/hip_runtime.h>
#include <stdint.h>

#define MDIM 2048
#define KDIM 4096
#define NDIM 8192
#define NG   32            // K / GROUP_SIZE
#define QROW 2048          // int32 per qweight row
#define NT   128           // K-tiles of BK=32
#define LSTR 36            // fused-fallback LDS row stride

typedef __attribute__((ext_vector_type(4))) float    f32x4;
typedef __attribute__((ext_vector_type(2))) _Float16 f16x2;
typedef __attribute__((ext_vector_type(8))) _Float16 f16x8;
typedef __attribute__((ext_vector_type(4))) int      i32x4;

#define CVT2(a,b) __builtin_bit_cast(f16x2, __builtin_amdgcn_cvt_pkrtz((a),(b)))
#define BCU(x)    __builtin_bit_cast(unsigned, (x))
#define BCH2(x)   __builtin_bit_cast(f16x2, (x))
#define MFMA16(A,B,C) __builtin_amdgcn_mfma_f32_16x16x32_f16((A),(B),(C),0,0,0)

__device__ __forceinline__ void gload_lds16(const void* g, void* l) {
  __builtin_amdgcn_global_load_lds(
      (const __attribute__((address_space(1))) void*)g,
      (__attribute__((address_space(3))) void*)l, 16, 0, 0);
}

// dequant 4 int32 (8 weights, identity k-order) -> 8 fp16 (verified r3/r6/r7/r8)
__device__ __forceinline__ uint4 dequant8(i32x4 q, float sf, float zf) {
  const _Float16 sh = (_Float16)sf;
  const _Float16 bh = (_Float16)(-zf * sf);
  const f16x2 s2 = {sh, sh}, b2 = {bh, bh};
  const f16x2 k2 = {(_Float16)1024.0f, (_Float16)1024.0f};
  uint4 r;
#define DQE(QV, DST) do {                                                   \
    unsigned Bb_ = (unsigned)(QV) & 0xFFu;                                  \
    unsigned bits_ = ((Bb_ | (Bb_ << 12)) & 0x000F000Fu) | 0x64006400u;     \
    DST = BCU((f16x2)((BCH2(bits_) - k2) * s2 + b2));                       \
  } while (0)
  DQE(q.x, r.x); DQE(q.y, r.y); DQE(q.z, r.z); DQE(q.w, r.w);
#undef DQE
  return r;
}

// ============ pass 1a: W dequant -> f16 [N][K] in ws ============
__global__ __launch_bounds__(256) void dequant_w_kernel(
    const int* __restrict__ qw, const float* __restrict__ scales,
    const float* __restrict__ zeros, _Float16* __restrict__ Wf)
{
  const size_t total = (size_t)NDIM * (KDIM / 8);
  for (size_t t = (size_t)blockIdx.x * blockDim.x + threadIdx.x; t < total;
       t += (size_t)gridDim.x * blockDim.x) {
    i32x4 q;
    __builtin_memcpy(&q, qw + 4 * t, 16);
    const int n = (int)(t >> 9);
    const int k = (int)((t & 511) << 3);
    const int g = k >> 7;
    uint4 w = dequant8(q, scales[n * NG + g], zeros[n * NG + g]);
    __builtin_memcpy(Wf + (size_t)n * KDIM + k, &w, 16);
  }
}

// ============ pass 1b: A f32 -> f16 [M][K] in ws ============
__global__ __launch_bounds__(256) void conv_a_kernel(
    const float* __restrict__ A, _Float16* __restrict__ Af)
{
  const size_t total = (size_t)MDIM * (KDIM / 8);
  for (size_t t = (size_t)blockIdx.x * blockDim.x + threadIdx.x; t < total;
       t += (size_t)gridDim.x * blockDim.x) {
    f32x4 v0, v1;
    __builtin_memcpy(&v0, A + 8 * t,     16);
    __builtin_memcpy(&v1, A + 8 * t + 4, 16);
    uint4 h;
    h.x = BCU(CVT2(v0.x, v0.y));
    h.y = BCU(CVT2(v0.z, v0.w));
    h.z = BCU(CVT2(v1.x, v1.y));
    h.w = BCU(CVT2(v1.z, v1.w));
    __builtin_memcpy(Af + 8 * t, &h, 16);
  }
}

// ============ pass 2: f16 GEMM, 256x256, depth-3 vmcnt pipeline + 4-phase interleave ============
// r8 skeleton (verified): 8 waves (2Mx4N), BK=32, 4 rotating 32KB LDS bufs,
// pre-swizzled source (chunk ^= (row>>1)&3), swizzled reads, vmcnt(8) gate.
// NEW: per K-tile, 4 quadrant-phases {ds_read subtile | 1 gload | barrier |
// setprio(1) 8 MFMA setprio(0)} -> LDS traffic overlaps the matrix pipe.
__global__ __launch_bounds__(512) void gemm_f16_kernel(
    const _Float16* __restrict__ Af,   // [M][K]
    const _Float16* __restrict__ Wf,   // [N][K]
    const float* __restrict__ bias,    // [N]
    float* __restrict__ out)           // [M][N] f32
{
  __shared__ __align__(16) _Float16 lds[4 * 16384];   // 128 KB

  const int tid  = threadIdx.x;
  const int wave = tid >> 6;
  const int lane = tid & 63;
  const int n0 = blockIdx.x << 8;
  const int m0 = blockIdx.y << 8;
  const int wm = (wave >> 2) << 7;   // 0 or 128
  const int wn = (wave & 3) << 6;    // 0,64,128,192

  f32x4 acc[8][4] = {};

  // staging source (pre-swizzled), linear LDS dest slot = tid*16B per region
  const int srow   = tid >> 2;
  const int schunk = (tid & 3) ^ ((tid >> 3) & 3);
  const _Float16* aS0 = Af + (size_t)(m0 + srow) * KDIM + schunk * 8;
  const _Float16* aS1 = Af + (size_t)(m0 + 128 + srow) * KDIM + schunk * 8;
  const _Float16* bS0 = Wf + (size_t)(n0 + srow) * KDIM + schunk * 8;
  const _Float16* bS1 = Wf + (size_t)(n0 + 128 + srow) * KDIM + schunk * 8;

#define ISSUE(T) do {                                                  \
    _Float16* d_ = &lds[(((T) & 3) << 14) + (wave << 9)];              \
    const size_t ko_ = (size_t)(T) << 5;                               \
    gload_lds16(aS0 + ko_, d_);                                        \
    gload_lds16(aS1 + ko_, d_ + 4096);                                 \
    gload_lds16(bS0 + ko_, d_ + 8192);                                 \
    gload_lds16(bS1 + ko_, d_ + 12288);                                \
  } while (0)

  // fragment read offsets (swizzled; verified zero-conflict in r8)
  const int fr = lane & 15;
  const int ck = (((lane >> 4) ^ ((fr >> 1) & 3))) << 3;
  int raOff[8], rbOff[4];
#pragma unroll
  for (int i = 0; i < 8; ++i) raOff[i] = (wm + 16 * i + fr) * 32 + ck;
#pragma unroll
  for (int j = 0; j < 4; ++j) rbOff[j] = 8192 + (wn + 16 * j + fr) * 32 + ck;

  // tail compute (r8 verbatim, no staging)
#define COMPUTE(T) do {                                                \
    const int bb_ = ((T) & 3) << 14;                                   \
    f16x8 bf_[4];                                                      \
    _Pragma("unroll")                                                  \
    for (int j = 0; j < 4; ++j)                                        \
      __builtin_memcpy(&bf_[j], &lds[bb_ + rbOff[j]], 16);             \
    _Pragma("unroll")                                                  \
    for (int q = 0; q < 4; ++q) {                                      \
      f16x8 a0_, a1_;                                                  \
      __builtin_memcpy(&a0_, &lds[bb_ + raOff[2 * q]], 16);            \
      __builtin_memcpy(&a1_, &lds[bb_ + raOff[2 * q + 1]], 16);        \
      __builtin_amdgcn_s_setprio(1);                                   \
      _Pragma("unroll")                                                \
      for (int j = 0; j < 4; ++j) {                                    \
        acc[2 * q][j] = MFMA16(a0_, bf_[j], acc[2 * q][j]);            \
        acc[2 * q + 1][j] = MFMA16(a1_, bf_[j], acc[2 * q + 1][j]);    \
      }                                                                \
      __builtin_amdgcn_s_setprio(0);                                   \
    }                                                                  \
  } while (0)

  // prologue: 3 tiles in flight
  ISSUE(0); ISSUE(1); ISSUE(2);

#pragma clang loop unroll(disable)
  for (int t = 0; t < NT - 3; ++t) {
    asm volatile("s_waitcnt vmcnt(8)" ::: "memory");   // tile t landed; t+1,t+2 in flight
    __builtin_amdgcn_s_barrier();
    const int bb = (t & 3) << 14;
    _Float16* sd = &lds[(((t + 3) & 3) << 14) + (wave << 9)];
    const size_t ko = (size_t)(t + 3) << 5;

    f16x8 bf[4], aA, aB;

    // ---- phase 0: B frags + A quadrant 0 | gload #0 ----
#pragma unroll
    for (int j = 0; j < 4; ++j)
      __builtin_memcpy(&bf[j], &lds[bb + rbOff[j]], 16);
    __builtin_memcpy(&aA, &lds[bb + raOff[0]], 16);
    __builtin_memcpy(&aB, &lds[bb + raOff[1]], 16);
    gload_lds16(aS0 + ko, sd);
    __builtin_amdgcn_s_barrier();
    __builtin_amdgcn_s_setprio(1);
#pragma unroll
    for (int j = 0; j < 4; ++j) {
      acc[0][j] = MFMA16(aA, bf[j], acc[0][j]);
      acc[1][j] = MFMA16(aB, bf[j], acc[1][j]);
    }
    __builtin_amdgcn_s_setprio(0);

    // ---- phase 1: A quadrant 1 | gload #1 ----
    __builtin_memcpy(&aA, &lds[bb + raOff[2]], 16);
    __builtin_memcpy(&aB, &lds[bb + raOff[3]], 16);
    gload_lds16(aS1 + ko, sd + 4096);
    __builtin_amdgcn_s_barrier();
    __builtin_amdgcn_s_setprio(1);
#pragma unroll
    for (int j = 0; j < 4; ++j) {
      acc[2][j] = MFMA16(aA, bf[j], acc[2][j]);
      acc[3][j] = MFMA16(aB, bf[j], acc[3][j]);
    }
    __builtin_amdgcn_s_setprio(0);

    // ---- phase 2: A quadrant 2 | gload #2 ----
    __builtin_memcpy(&aA, &lds[bb + raOff[4]], 16);
    __builtin_memcpy(&aB, &lds[bb + raOff[5]], 16);
    gload_lds16(bS0 + ko, sd + 8192);
    __builtin_amdgcn_s_barrier();
    __builtin_amdgcn_s_setprio(1);
#pragma unroll
    for (int j = 0; j < 4; ++j) {
      acc[4][j] = MFMA16(aA, bf[j], acc[4][j]);
      acc[5][j] = MFMA16(aB, bf[j], acc[5][j]);
    }
    __builtin_amdgcn_s_setprio(0);

    // ---- phase 3: A quadrant 3 | gload #3 ----
    __builtin_memcpy(&aA, &lds[bb + raOff[6]], 16);
    __builtin_memcpy(&aB, &lds[bb + raOff[7]], 16);
    gload_lds16(bS1 + ko, sd + 12288);
    __builtin_amdgcn_s_barrier();
    __builtin_amdgcn_s_setprio(1);
#pragma unroll
    for (int j = 0; j < 4; ++j) {
      acc[6][j] = MFMA16(aA, bf[j], acc[6][j]);
      acc[7][j] = MFMA16(aB, bf[j], acc[7][j]);
    }
    __builtin_amdgcn_s_setprio(0);
  }

  // tail: drain pipeline (r8 verbatim)
  asm volatile("s_waitcnt vmcnt(8)" ::: "memory");
  __builtin_amdgcn_s_barrier();
  COMPUTE(NT - 3);
  asm volatile("s_waitcnt vmcnt(4)" ::: "memory");
  __builtin_amdgcn_s_barrier();
  COMPUTE(NT - 2);
  asm volatile("s_waitcnt vmcnt(0)" ::: "memory");
  __builtin_amdgcn_s_barrier();
  COMPUTE(NT - 1);

#undef ISSUE
#undef COMPUTE

  // epilogue: C/D col = lane&15, row = (lane>>4)*4 + reg
  const int cr = (lane >> 4) << 2;
  const int cc = lane & 15;
#pragma unroll
  for (int j = 0; j < 4; ++j) {
    const int n = n0 + wn + j * 16 + cc;
    const float bv = bias[n];
#pragma unroll
    for (int i = 0; i < 8; ++i) {
      const int mrow = m0 + wm + i * 16 + cr;
#pragma unroll
      for (int r = 0; r < 4; ++r)
        out[(size_t)(mrow + r) * NDIM + n] = acc[i][j][r] + bv;
    }
  }
}

// ============ fused fallback (round-6 kernel, verified PASS) ============
__global__ __launch_bounds__(256, 4) void qlin_fused_kernel(
    const float* __restrict__ A, const int* __restrict__ qw,
    const float* __restrict__ scales, const float* __restrict__ zeros,
    const float* __restrict__ bias, float* __restrict__ out)
{
  __shared__ _Float16 As[2][128 * LSTR];
  __shared__ _Float16 Bs[2][128 * LSTR];

  const int tid  = threadIdx.x;
  const int wave = tid >> 6;
  const int lane = tid & 63;
  const int n0 = blockIdx.x << 7;
  const int m0 = blockIdx.y << 7;
  const int wm = (wave >> 1) << 6;
  const int wn = (wave & 1) << 6;

  f32x4 acc[4][4] = {};

  const int r4 = tid >> 2;
  const int c4 = tid & 3;

  const float* aP0 = A + (size_t)(m0 + r4) * KDIM + c4 * 8;
  const float* aP1 = aP0 + (size_t)64 * KDIM;
  const int*   qP0 = qw + (size_t)(n0 + r4) * QROW + c4 * 4;
  const int*   qP1 = qP0 + (size_t)64 * QROW;
  const float* sP0 = scales + (size_t)(n0 + r4) * NG;
  const float* zP0 = zeros  + (size_t)(n0 + r4) * NG;
  const float* sP1 = sP0 + (size_t)64 * NG;
  const float* zP1 = zP0 + (size_t)64 * NG;

  const int aD0 = r4 * LSTR + c4 * 8;
  const int aD1 = (r4 + 64) * LSTR + c4 * 8;

  const int fr = lane & 15;
  const int k0 = (lane >> 4) * 8;
  const int ra0 = (wm +  0 + fr) * LSTR + k0;
  const int ra1 = (wm + 16 + fr) * LSTR + k0;
  const int ra2 = (wm + 32 + fr) * LSTR + k0;
  const int ra3 = (wm + 48 + fr) * LSTR + k0;
  const int rb0 = (wn +  0 + fr) * LSTR + k0;
  const int rb1 = (wn + 16 + fr) * LSTR + k0;
  const int rb2 = (wn + 32 + fr) * LSTR + k0;
  const int rb3 = (wn + 48 + fr) * LSTR + k0;

  f32x4 pa0, pa1, pa2, pa3;
  i32x4 pq0, pq1;
  float psf0, pzf0, psf1, pzf1;

#define ISSUE(KT) do {                                                        \
    __builtin_memcpy(&pa0, aP0 + (size_t)(KT) * 32,     16);                  \
    __builtin_memcpy(&pa1, aP0 + (size_t)(KT) * 32 + 4, 16);                  \
    __builtin_memcpy(&pa2, aP1 + (size_t)(KT) * 32,     16);                  \
    __builtin_memcpy(&pa3, aP1 + (size_t)(KT) * 32 + 4, 16);                  \
    __builtin_memcpy(&pq0, qP0 + (size_t)(KT) * 16, 16);                      \
    __builtin_memcpy(&pq1, qP1 + (size_t)(KT) * 16, 16);                      \
    const int g_ = (KT) >> 2;                                                 \
    psf0 = sP0[g_]; pzf0 = zP0[g_];                                           \
    psf1 = sP1[g_]; pzf1 = zP1[g_];                                           \
  } while (0)

#define STAGE(P) do {                                                         \
    uint4 aw0_;                                                               \
    aw0_.x = BCU(CVT2(pa0.x, pa0.y));                                         \
    aw0_.y = BCU(CVT2(pa0.z, pa0.w));                                         \
    aw0_.z = BCU(CVT2(pa1.x, pa1.y));                                         \
    aw0_.w = BCU(CVT2(pa1.z, pa1.w));                                         \
    __builtin_memcpy(&As[P][aD0], &aw0_, 16);                                 \
    uint4 aw1_;                                                               \
    aw1_.x = BCU(CVT2(pa2.x, pa2.y));                                         \
    aw1_.y = BCU(CVT2(pa2.z, pa2.w));                                         \
    aw1_.z = BCU(CVT2(pa3.x, pa3.y));                                         \
    aw1_.w = BCU(CVT2(pa3.z, pa3.w));                                         \
    __builtin_memcpy(&As[P][aD1], &aw1_, 16);                                 \
    uint4 bw0_ = dequant8(pq0, psf0, pzf0);                                   \
    __builtin_memcpy(&Bs[P][aD0], &bw0_, 16);                                 \
    uint4 bw1_ = dequant8(pq1, psf1, pzf1);                                   \
    __builtin_memcpy(&Bs[P][aD1], &bw1_, 16);                                 \
  } while (0)

#define COMPUTE(P) do {                                                       \
    f16x8 af[4], bfr[4];                                                      \
    __builtin_memcpy(&af[0], &As[P][ra0], 16);                                \
    __builtin_memcpy(&af[1], &As[P][ra1], 16);                                \
    __builtin_memcpy(&af[2], &As[P][ra2], 16);                                \
    __builtin_memcpy(&af[3], &As[P][ra3], 16);                                \
    __builtin_memcpy(&bfr[0], &Bs[P][rb0], 16);                               \
    __builtin_memcpy(&bfr[1], &Bs[P][rb1], 16);                               \
    __builtin_memcpy(&bfr[2], &Bs[P][rb2], 16);                               \
    __builtin_memcpy(&bfr[3], &Bs[P][rb3], 16);                               \
    _Pragma("unroll")                                                         \
    for (int i = 0; i < 4; ++i)                                               \
      _Pragma("unroll")                                                       \
      for (int j = 0; j < 4; ++j)                                             \
        acc[i][j] = MFMA16(af[i], bfr[j], acc[i][j]);                         \
  } while (0)

  ISSUE(0);
  STAGE(0);
  __syncthreads();

#pragma clang loop unroll(disable)
  for (int kt = 0; kt < 127; ++kt) {
    const int p = kt & 1;
    ISSUE(kt + 1);
    COMPUTE(p);
    STAGE(p ^ 1);
    __syncthreads();
  }
  COMPUTE(1);

#undef ISSUE
#undef STAGE
#undef COMPUTE

  const int cr = (lane >> 4) << 2;
  const int cc = lane & 15;
#pragma unroll
  for (int j = 0; j < 4; ++j) {
    const int n = n0 + wn + j * 16 + cc;
    const float bv = bias[n];
#pragma unroll
    for (int i = 0; i < 4; ++i) {
      const int mrow = m0 + wm + i * 16 + cr;
#pragma unroll
      for (int r = 0; r < 4; ++r)
        out[(size_t)(mrow + r) * NDIM + n] = acc[i][j][r] + bv;
    }
  }
}

extern "C" void kernel_launch(void* const* d_in, const int* in_sizes, int n_in,
                              void* d_out, int out_size, void* d_ws, size_t ws_size,
                              hipStream_t stream) {
  const float* A      = (const float*)d_in[0];
  const int*   qwp    = (const int*)d_in[1];
  const float* scales = (const float*)d_in[2];
  const float* zerosp = (const float*)d_in[3];
  const float* biasp  = (const float*)d_in[4];
  float*       outp   = (float*)d_out;

  const size_t needW = (size_t)NDIM * KDIM * sizeof(_Float16);   // 64 MB
  const size_t needA = (size_t)MDIM * KDIM * sizeof(_Float16);   // 16 MB

  if (ws_size >= needW + needA) {
    _Float16* Wf = (_Float16*)d_ws;
    _Float16* Af = (_Float16*)((char*)d_ws + needW);
    dequant_w_kernel<<<2048, 256, 0, stream>>>(qwp, scales, zerosp, Wf);
    conv_a_kernel<<<2048, 256, 0, stream>>>(A, Af);
    dim3 grid(NDIM / 256, MDIM / 256);  // 32 x 8 = 256 blocks (1/CU)
    gemm_f16_kernel<<<grid, 512, 0, stream>>>(Af, Wf, biasp, outp);
  } else {
    dim3 grid(NDIM / 128, MDIM / 128);
    qlin_fused_kernel<<<grid, 256, 0, stream>>>(A, qwp, scales, zerosp, biasp, outp);
  }
}